// Round 2
// baseline (10252.294 us; speedup 1.0000x reference)
//
#include <hip/hip_runtime.h>
#include <stdint.h>

// Problem constants
#define NT 1024
#define NB 64
#define ND 128
#define NH 512
#define NPAIR (NH / 2)   // 256 8-byte units per row

typedef float f32x4  __attribute__((ext_vector_type(4)));
typedef short bf16x8 __attribute__((ext_vector_type(8)));
typedef unsigned int uint32x4 __attribute__((ext_vector_type(4)));
typedef unsigned long long u64;

// round-to-nearest-even f32 -> bf16
__device__ __forceinline__ unsigned short f2bf(float f) {
  uint32_t u = __float_as_uint(f);
  u += 0x7fffu + ((u >> 16) & 1u);
  return (unsigned short)(u >> 16);
}

__device__ __forceinline__ bf16x8 cvt8(f32x4 a, f32x4 b) {
  bf16x8 r;
  r[0] = (short)f2bf(a[0]); r[1] = (short)f2bf(a[1]);
  r[2] = (short)f2bf(a[2]); r[3] = (short)f2bf(a[3]);
  r[4] = (short)f2bf(b[0]); r[5] = (short)f2bf(b[1]);
  r[6] = (short)f2bf(b[2]); r[7] = (short)f2bf(b[3]);
  return r;
}

// Issue 16 tagged-unit loads (one "group" = 4 K-chunks of 32).
// base already includes (slot,row,quad) offsets; unit offset for chunk kk,
// unit j is kk*16 + j (j=0..3 within this lane's quad segment).
__device__ __forceinline__ void load_group(const u64* __restrict__ base, int g,
                                           u64* u) {
#pragma unroll
  for (int i = 0; i < 16; ++i)
    u[i] = __hip_atomic_load(base + g * 64 + (i >> 2) * 16 + (i & 3),
                             __ATOMIC_RELAXED, __HIP_MEMORY_SCOPE_AGENT);
}

// Spin until all 16 units carry tag t, then feed 4 MFMAs.
__device__ __forceinline__ void consume_group(u64* u, int g,
                                              const u64* __restrict__ base,
                                              int t, f32x4& acc,
                                              const bf16x8* Bh) {
  for (;;) {
    uint32_t m = 0;
#pragma unroll
    for (int i = 0; i < 16; ++i)
      m |= (uint32_t)(u[i] >> 32) ^ (uint32_t)t;
    if (m == 0) break;
    load_group(base, g, u);  // re-poll (only divergent lanes re-execute)
  }
#pragma unroll
  for (int c = 0; c < 4; ++c) {
    uint32x4 p = {(uint32_t)u[c * 4 + 0], (uint32_t)u[c * 4 + 1],
                  (uint32_t)u[c * 4 + 2], (uint32_t)u[c * 4 + 3]};
    acc = __builtin_amdgcn_mfma_f32_16x16x32_bf16(
        __builtin_bit_cast(bf16x8, p), Bh[g * 4 + c], acc, 0, 0, 0);
  }
}

// Persistent RNN kernel, LL-tagged communication (no fences, no barriers).
// Grid: 32 WGs x 256 threads. WG wg: rg = wg>>3 (16 batch rows), cg = wg&7
// (64 hidden cols). Wave (wv) tile: 16x16. Weights stationary in VGPRs.
// fr moves via llbuf[2][B][NPAIR] of 8B units: [tag:32 | bf16 pair:32].
// Tag t == "this is fr_t". Published unit payload is an MFMA function of all
// 512 k-inputs of that step => tag t visible implies producer finished
// reading slot (t-1)&1 => overwriting slot (t+1)&1 is race-free.
__global__ __launch_bounds__(256, 1) void rnn_persistent(
    const float* __restrict__ input,   // [T,B,D]
    const float* __restrict__ W_in,    // [H,D]
    const float* __restrict__ b_in,    // [H]
    const float* __restrict__ W_hid,   // [H,H]
    const float* __restrict__ b_hid,   // [H]
    float* __restrict__ out,           // [T,B,H] fp32
    u64* __restrict__ llbuf)           // [2][B][NPAIR]
{
  const int wg   = blockIdx.x;   // 0..31
  const int rg   = wg >> 3;      // row group 0..3
  const int cg   = wg & 7;       // col group 0..7
  const int tid  = threadIdx.x;
  const int wv   = tid >> 6;     // wave 0..3
  const int lane = tid & 63;
  const int col  = lane & 15;
  const int quad = lane >> 4;
  const int kq   = quad * 8;

  const int bA = rg * 16 + col;           // A-fragment batch row
  const int gB = cg * 64 + wv * 16 + col; // B-fragment / C column
  const int bC = rg * 16 + quad * 4;      // C rows: bC + r

  // ---- stationary weights: B-fragments in registers (bf16) ----
  bf16x8 Bh[16];
#pragma unroll
  for (int kk = 0; kk < 16; ++kk) {
    const float* p = W_hid + (size_t)gB * NH + kk * 32 + kq;
    Bh[kk] = cvt8(*(const f32x4*)p, *(const f32x4*)(p + 4));
  }
  bf16x8 Bi[4];
#pragma unroll
  for (int kk = 0; kk < 4; ++kk) {
    const float* p = W_in + (size_t)gB * ND + kk * 32 + kq;
    Bi[kk] = cvt8(*(const f32x4*)p, *(const f32x4*)(p + 4));
  }
  const float blane = b_hid[gB] + b_in[gB];

  float v0 = 0.f, v1 = 0.f, v2 = 0.f, v3 = 0.f;
  u64 ua[16], ub[16];

#pragma unroll 1
  for (int t = 0; t < NT; ++t) {
    // prefetch this step's input slice (independent of fr)
    const float* ip = input + ((size_t)t * NB + bA) * ND + kq;
    f32x4 x0 = *(const f32x4*)(ip);
    f32x4 x1 = *(const f32x4*)(ip + 4);
    f32x4 x2 = *(const f32x4*)(ip + 32);
    f32x4 x3 = *(const f32x4*)(ip + 36);
    f32x4 x4 = *(const f32x4*)(ip + 64);
    f32x4 x5 = *(const f32x4*)(ip + 68);
    f32x4 x6 = *(const f32x4*)(ip + 96);
    f32x4 x7 = *(const f32x4*)(ip + 100);

    const u64* cbase =
        llbuf + (size_t)((t & 1) * NB + bA) * NPAIR + quad * 4;

    if (t > 0) load_group(cbase, 0, ua);  // in flight during input MFMAs

    f32x4 acc = {0.f, 0.f, 0.f, 0.f};
    acc = __builtin_amdgcn_mfma_f32_16x16x32_bf16(cvt8(x0, x1), Bi[0], acc, 0, 0, 0);
    acc = __builtin_amdgcn_mfma_f32_16x16x32_bf16(cvt8(x2, x3), Bi[1], acc, 0, 0, 0);
    acc = __builtin_amdgcn_mfma_f32_16x16x32_bf16(cvt8(x4, x5), Bi[2], acc, 0, 0, 0);
    acc = __builtin_amdgcn_mfma_f32_16x16x32_bf16(cvt8(x6, x7), Bi[3], acc, 0, 0, 0);

    if (t > 0) {
      load_group(cbase, 1, ub);
      consume_group(ua, 0, cbase, t, acc, Bh);
      load_group(cbase, 2, ua);
      consume_group(ub, 1, cbase, t, acc, Bh);
      load_group(cbase, 3, ub);
      consume_group(ua, 2, cbase, t, acc, Bh);
      consume_group(ub, 3, cbase, t, acc, Bh);
    }

    // v = 0.9 v + 0.1 (S + b); fr = relu(v)
    v0 = 0.9f * v0 + 0.1f * (acc[0] + blane);
    v1 = 0.9f * v1 + 0.1f * (acc[1] + blane);
    v2 = 0.9f * v2 + 0.1f * (acc[2] + blane);
    v3 = 0.9f * v3 + 0.1f * (acc[3] + blane);
    float f0 = fmaxf(v0, 0.f), f1 = fmaxf(v1, 0.f);
    float f2 = fmaxf(v2, 0.f), f3 = fmaxf(v3, 0.f);

    // stream output (fp32, plain cached stores)
    float* op = out + ((size_t)t * NB + bC) * NH + gB;
    op[0]      = f0;
    op[NH]     = f1;
    op[2 * NH] = f2;
    op[3 * NH] = f3;

    // publish fr_{t+1}: pair with neighbor lane (cols gB, gB^1), even lanes
    // store one 8B unit per row: [tag=t+1 | bf16(self) | bf16(partner)<<16]
    float p0 = __shfl_xor(f0, 1, 64);
    float p1 = __shfl_xor(f1, 1, 64);
    float p2 = __shfl_xor(f2, 1, 64);
    float p3 = __shfl_xor(f3, 1, 64);
    if (!(lane & 1)) {
      const u64 tagw = ((u64)(uint32_t)(t + 1)) << 32;
      u64* pb = llbuf + (size_t)((~t & 1) * NB + bC) * NPAIR + (gB >> 1);
      u64 w0 = tagw | (u64)((uint32_t)f2bf(f0) | ((uint32_t)f2bf(p0) << 16));
      u64 w1 = tagw | (u64)((uint32_t)f2bf(f1) | ((uint32_t)f2bf(p1) << 16));
      u64 w2 = tagw | (u64)((uint32_t)f2bf(f2) | ((uint32_t)f2bf(p2) << 16));
      u64 w3 = tagw | (u64)((uint32_t)f2bf(f3) | ((uint32_t)f2bf(p3) << 16));
      __hip_atomic_store(pb + 0 * NPAIR, w0, __ATOMIC_RELAXED, __HIP_MEMORY_SCOPE_AGENT);
      __hip_atomic_store(pb + 1 * NPAIR, w1, __ATOMIC_RELAXED, __HIP_MEMORY_SCOPE_AGENT);
      __hip_atomic_store(pb + 2 * NPAIR, w2, __ATOMIC_RELAXED, __HIP_MEMORY_SCOPE_AGENT);
      __hip_atomic_store(pb + 3 * NPAIR, w3, __ATOMIC_RELAXED, __HIP_MEMORY_SCOPE_AGENT);
    }
  }
}

extern "C" void kernel_launch(void* const* d_in, const int* in_sizes, int n_in,
                              void* d_out, int out_size, void* d_ws, size_t ws_size,
                              hipStream_t stream) {
  const float* input = (const float*)d_in[0];  // [T,B,D]
  const float* W_in  = (const float*)d_in[1];  // [H,D]
  const float* b_in  = (const float*)d_in[2];  // [H]
  const float* W_hid = (const float*)d_in[3];  // [H,H]
  const float* b_hid = (const float*)d_in[4];  // [H]
  float* out = (float*)d_out;

  // workspace: llbuf[2][B][NPAIR] u64 = 256 KB. Poison 0xAA.. gives tag
  // 0xAAAAAAAA != any t in [1,1024] -> consumers block until real data.
  u64* llbuf = (u64*)d_ws;

  hipLaunchKernelGGL(rnn_persistent, dim3(32), dim3(256), 0, stream,
                     input, W_in, b_in, W_hid, b_hid, out, llbuf);
}

// Round 3
// 4411.797 us; speedup vs baseline: 2.3238x; 2.3238x over previous
//
#include <hip/hip_runtime.h>
#include <stdint.h>

// Problem constants
#define NT 1024
#define NB 64
#define ND 128
#define NH 512
#define NPAIR (NH / 2)   // 256 8-byte units per row

typedef float f32x4  __attribute__((ext_vector_type(4)));
typedef short bf16x8 __attribute__((ext_vector_type(8)));
typedef unsigned int uint32x4 __attribute__((ext_vector_type(4)));
typedef unsigned long long u64;

// round-to-nearest-even f32 -> bf16
__device__ __forceinline__ unsigned short f2bf(float f) {
  uint32_t u = __float_as_uint(f);
  u += 0x7fffu + ((u >> 16) & 1u);
  return (unsigned short)(u >> 16);
}

__device__ __forceinline__ bf16x8 cvt8(f32x4 a, f32x4 b) {
  bf16x8 r;
  r[0] = (short)f2bf(a[0]); r[1] = (short)f2bf(a[1]);
  r[2] = (short)f2bf(a[2]); r[3] = (short)f2bf(a[3]);
  r[4] = (short)f2bf(b[0]); r[5] = (short)f2bf(b[1]);
  r[6] = (short)f2bf(b[2]); r[7] = (short)f2bf(b[3]);
  return r;
}

// Load this wave's 16 tagged units (its 4 K-chunks). base already includes
// (slot,row,quad*4) offsets; unit offset for local chunk c, unit j is
// (wv*4+c)*16 + j.
__device__ __forceinline__ void load_group(const u64* __restrict__ base, int g,
                                           u64* u) {
#pragma unroll
  for (int i = 0; i < 16; ++i)
    u[i] = __hip_atomic_load(base + g * 64 + (i >> 2) * 16 + (i & 3),
                             __ATOMIC_RELAXED, __HIP_MEMORY_SCOPE_AGENT);
}

// Persistent RNN kernel, LL-tagged communication + cooperative LDS staging.
// Grid: 32 WGs x 256 threads. WG wg: rg = wg>>3 (16 batch rows), cg = wg&7
// (64 hidden cols). Wave wv owns a 16x16 C tile. W_hid/W_in B-frags in VGPRs.
// fr moves via llbuf[2][B][NPAIR] of 8B units [tag:32 | bf16 pair:32].
// Per step each wave polls/loads only chunks [wv*4, wv*4+4), verifies tags,
// deposits payloads in LDS (identity lane mapping), one barrier, then all
// waves read A-frags from LDS. 4x less fabric traffic + 1 detect per step.
__global__ __launch_bounds__(256, 1) void rnn_persistent(
    const float* __restrict__ input,   // [T,B,D]
    const float* __restrict__ W_in,    // [H,D]
    const float* __restrict__ b_in,    // [H]
    const float* __restrict__ W_hid,   // [H,H]
    const float* __restrict__ b_hid,   // [H]
    float* __restrict__ out,           // [T,B,H] fp32
    u64* __restrict__ llbuf)           // [2][B][NPAIR]
{
  // [slot][chunk][lane][4 x u32 payload] = 32 KB
  __shared__ uint32x4 lds[2][16][64];

  const int wg   = blockIdx.x;   // 0..31
  const int rg   = wg >> 3;      // row group 0..3
  const int cg   = wg & 7;       // col group 0..7
  const int tid  = threadIdx.x;
  const int wv   = tid >> 6;     // wave 0..3
  const int lane = tid & 63;
  const int col  = lane & 15;
  const int quad = lane >> 4;
  const int kq   = quad * 8;

  const int bA = rg * 16 + col;           // fr row this lane stages/uses
  const int gB = cg * 64 + wv * 16 + col; // B-fragment / C column
  const int bC = rg * 16 + quad * 4;      // C rows: bC + r

  // ---- stationary weights: B-fragments in registers (bf16) ----
  bf16x8 Bh[16];
#pragma unroll
  for (int kk = 0; kk < 16; ++kk) {
    const float* p = W_hid + (size_t)gB * NH + kk * 32 + kq;
    Bh[kk] = cvt8(*(const f32x4*)p, *(const f32x4*)(p + 4));
  }
  bf16x8 Bi[4];
#pragma unroll
  for (int kk = 0; kk < 4; ++kk) {
    const float* p = W_in + (size_t)gB * ND + kk * 32 + kq;
    Bi[kk] = cvt8(*(const f32x4*)p, *(const f32x4*)(p + 4));
  }
  const float blane = b_hid[gB] + b_in[gB];

  float v0 = 0.f, v1 = 0.f, v2 = 0.f, v3 = 0.f;
  u64 ua[16];

#pragma unroll 1
  for (int t = 0; t < NT; ++t) {
    // prefetch this step's input slice (independent of fr)
    const float* ip = input + ((size_t)t * NB + bA) * ND + kq;
    f32x4 x0 = *(const f32x4*)(ip);
    f32x4 x1 = *(const f32x4*)(ip + 4);
    f32x4 x2 = *(const f32x4*)(ip + 32);
    f32x4 x3 = *(const f32x4*)(ip + 36);
    f32x4 x4 = *(const f32x4*)(ip + 64);
    f32x4 x5 = *(const f32x4*)(ip + 68);
    f32x4 x6 = *(const f32x4*)(ip + 96);
    f32x4 x7 = *(const f32x4*)(ip + 100);

    const u64* cbase =
        llbuf + (size_t)((t & 1) * NB + bA) * NPAIR + quad * 4;

    if (t > 0) load_group(cbase, wv, ua);  // in flight during input MFMAs

    f32x4 acc = {0.f, 0.f, 0.f, 0.f};
    acc = __builtin_amdgcn_mfma_f32_16x16x32_bf16(cvt8(x0, x1), Bi[0], acc, 0, 0, 0);
    acc = __builtin_amdgcn_mfma_f32_16x16x32_bf16(cvt8(x2, x3), Bi[1], acc, 0, 0, 0);
    acc = __builtin_amdgcn_mfma_f32_16x16x32_bf16(cvt8(x4, x5), Bi[2], acc, 0, 0, 0);
    acc = __builtin_amdgcn_mfma_f32_16x16x32_bf16(cvt8(x6, x7), Bi[3], acc, 0, 0, 0);

    if (t > 0) {
      // spin (throttled) until this wave's 16 units all carry tag t
      for (;;) {
        uint32_t m = 0;
#pragma unroll
        for (int i = 0; i < 16; ++i)
          m |= (uint32_t)(ua[i] >> 32) ^ (uint32_t)t;
        if (m == 0) break;
        __builtin_amdgcn_s_sleep(1);
        load_group(cbase, wv, ua);
      }
      // deposit payloads: stager lane (quad,col) holds exactly the A-frag
      // reader lane (quad,col) needs for chunks wv*4+c.
#pragma unroll
      for (int c = 0; c < 4; ++c) {
        uint32x4 p = {(uint32_t)ua[c * 4 + 0], (uint32_t)ua[c * 4 + 1],
                      (uint32_t)ua[c * 4 + 2], (uint32_t)ua[c * 4 + 3]};
        lds[t & 1][wv * 4 + c][lane] = p;
      }
      __syncthreads();
      // recurrent MFMAs: A-frags from LDS (lane-contiguous b128, no conflicts)
#pragma unroll
      for (int kk = 0; kk < 16; ++kk) {
        uint32x4 p = lds[t & 1][kk][lane];
        acc = __builtin_amdgcn_mfma_f32_16x16x32_bf16(
            __builtin_bit_cast(bf16x8, p), Bh[kk], acc, 0, 0, 0);
      }
    }

    // v = 0.9 v + 0.1 (S + b); fr = relu(v)
    v0 = 0.9f * v0 + 0.1f * (acc[0] + blane);
    v1 = 0.9f * v1 + 0.1f * (acc[1] + blane);
    v2 = 0.9f * v2 + 0.1f * (acc[2] + blane);
    v3 = 0.9f * v3 + 0.1f * (acc[3] + blane);
    float f0 = fmaxf(v0, 0.f), f1 = fmaxf(v1, 0.f);
    float f2 = fmaxf(v2, 0.f), f3 = fmaxf(v3, 0.f);

    // stream output (fp32, plain cached stores)
    float* op = out + ((size_t)t * NB + bC) * NH + gB;
    op[0]      = f0;
    op[NH]     = f1;
    op[2 * NH] = f2;
    op[3 * NH] = f3;

    // publish fr_{t+1}: pair with neighbor lane (cols gB, gB^1), even lanes
    // store one 8B unit per row: [tag=t+1 | bf16(self) | bf16(partner)<<16]
    float p0 = __shfl_xor(f0, 1, 64);
    float p1 = __shfl_xor(f1, 1, 64);
    float p2 = __shfl_xor(f2, 1, 64);
    float p3 = __shfl_xor(f3, 1, 64);
    if (!(lane & 1)) {
      const u64 tagw = ((u64)(uint32_t)(t + 1)) << 32;
      u64* pb = llbuf + (size_t)(((t + 1) & 1) * NB + bC) * NPAIR + (gB >> 1);
      u64 w0 = tagw | (u64)((uint32_t)f2bf(f0) | ((uint32_t)f2bf(p0) << 16));
      u64 w1 = tagw | (u64)((uint32_t)f2bf(f1) | ((uint32_t)f2bf(p1) << 16));
      u64 w2 = tagw | (u64)((uint32_t)f2bf(f2) | ((uint32_t)f2bf(p2) << 16));
      u64 w3 = tagw | (u64)((uint32_t)f2bf(f3) | ((uint32_t)f2bf(p3) << 16));
      __hip_atomic_store(pb + 0 * NPAIR, w0, __ATOMIC_RELAXED, __HIP_MEMORY_SCOPE_AGENT);
      __hip_atomic_store(pb + 1 * NPAIR, w1, __ATOMIC_RELAXED, __HIP_MEMORY_SCOPE_AGENT);
      __hip_atomic_store(pb + 2 * NPAIR, w2, __ATOMIC_RELAXED, __HIP_MEMORY_SCOPE_AGENT);
      __hip_atomic_store(pb + 3 * NPAIR, w3, __ATOMIC_RELAXED, __HIP_MEMORY_SCOPE_AGENT);
    }
  }
}

extern "C" void kernel_launch(void* const* d_in, const int* in_sizes, int n_in,
                              void* d_out, int out_size, void* d_ws, size_t ws_size,
                              hipStream_t stream) {
  const float* input = (const float*)d_in[0];  // [T,B,D]
  const float* W_in  = (const float*)d_in[1];  // [H,D]
  const float* b_in  = (const float*)d_in[2];  // [H]
  const float* W_hid = (const float*)d_in[3];  // [H,H]
  const float* b_hid = (const float*)d_in[4];  // [H]
  float* out = (float*)d_out;

  // workspace: llbuf[2][B][NPAIR] u64 = 256 KB. Poison 0xAA.. gives tag
  // 0xAAAAAAAA != any t in [1,1024] -> consumers block until real data.
  u64* llbuf = (u64*)d_ws;

  hipLaunchKernelGGL(rnn_persistent, dim3(32), dim3(256), 0, stream,
                     input, W_in, b_in, W_hid, b_hid, out, llbuf);
}